// Round 1
// baseline (299.891 us; speedup 1.0000x reference)
//
#include <hip/hip_runtime.h>

#define BB 8
#define CC 256
#define ICH 128
#define TT 4096
#define SS 2048
static constexpr float BN_EPS = 1e-5f;
static constexpr float INV_S  = 1.0f / 2048.0f;
static constexpr float INV_BT = 1.0f / 32768.0f;   // 1/(B*T)

// ---------------------------------------------------------------------------
// k1: fused conv1x1 (phi & g stacked as 256 out channels) + maxpool2
//     phi_g[b][o][s] = max_p( sum_c W[o][c] * x[b][c][2s+p] ) + bias[o]
// grid (32 t-tiles, 4 o-tiles, 8 b), block 256
// ---------------------------------------------------------------------------
__global__ __launch_bounds__(256) void k1_conv_pool(
    const float* __restrict__ x, const float* __restrict__ phi_w,
    const float* __restrict__ phi_b, const float* __restrict__ g_w,
    const float* __restrict__ g_b, float* __restrict__ phi_g)
{
    __shared__ float Xs[64][128];   // [k][t_local] 32 KB
    __shared__ float Ws[64][65];    // [k][o] transposed, padded

    const int b  = blockIdx.z;
    const int ob = blockIdx.y * 64;     // fused out-channel base (0..255)
    const int tb = blockIdx.x * 128;    // pre-pool t base
    const int tid = threadIdx.x;
    const int tx = tid & 15, ty = tid >> 4;

    const float* W    = (ob < ICH) ? (phi_w + (size_t)ob * CC) : (g_w + (size_t)(ob - ICH) * CC);
    const float* bias = (ob < ICH) ? (phi_b + ob) : (g_b + (ob - ICH));

    float acc[4][4][2];
    #pragma unroll
    for (int i = 0; i < 4; ++i)
        #pragma unroll
        for (int j = 0; j < 4; ++j) { acc[i][j][0] = 0.f; acc[i][j][1] = 0.f; }

    for (int kc = 0; kc < 4; ++kc) {
        const float* xsrc = x + ((size_t)b * CC + kc * 64) * TT + tb;
        #pragma unroll
        for (int r = 0; r < 8; ++r) {                 // 2048 float4 / 256 thr
            int idx = tid + 256 * r;
            int k = idx >> 5, c4 = idx & 31;
            *(float4*)(&Xs[k][c4 * 4]) = *(const float4*)(xsrc + (size_t)k * TT + c4 * 4);
        }
        #pragma unroll
        for (int r = 0; r < 4; ++r) {                 // 1024 float4 / 256 thr
            int idx = tid + 256 * r;
            int o = idx >> 4, c4 = idx & 15;
            float4 v = *(const float4*)(W + (size_t)o * CC + kc * 64 + c4 * 4);
            Ws[c4 * 4 + 0][o] = v.x; Ws[c4 * 4 + 1][o] = v.y;
            Ws[c4 * 4 + 2][o] = v.z; Ws[c4 * 4 + 3][o] = v.w;
        }
        __syncthreads();
        for (int kk = 0; kk < 64; ++kk) {
            float wv[4];
            #pragma unroll
            for (int i = 0; i < 4; ++i) wv[i] = Ws[kk][ty + 16 * i];
            #pragma unroll
            for (int j = 0; j < 4; ++j) {
                const float2 xv = *(const float2*)(&Xs[kk][2 * (tx + 16 * j)]);
                #pragma unroll
                for (int i = 0; i < 4; ++i) {
                    acc[i][j][0] += wv[i] * xv.x;
                    acc[i][j][1] += wv[i] * xv.y;
                }
            }
        }
        __syncthreads();
    }

    const int sb = blockIdx.x * 64;
    #pragma unroll
    for (int i = 0; i < 4; ++i) {
        int o = ty + 16 * i;
        float bv = bias[o];
        float* dst = phi_g + ((size_t)b * CC + ob + o) * SS + sb;
        #pragma unroll
        for (int j = 0; j < 4; ++j)
            dst[tx + 16 * j] = fmaxf(acc[i][j][0], acc[i][j][1]) + bv;
    }
}

// ---------------------------------------------------------------------------
// k2: Gram partials  Mpart[b][kc][c'][c] = sum_{s in chunk kc (256)} phi[c'][s]*g[c][s]
// grid (4 tiles(2x2 of 64), 8 kc, 8 b), block 256
// ---------------------------------------------------------------------------
__global__ __launch_bounds__(256) void k2_gram(
    const float* __restrict__ phi_g, float* __restrict__ Mpart)
{
    __shared__ float Ps[64][68];
    __shared__ float Gs[64][68];
    const int b = blockIdx.z;
    const int kc = blockIdx.y;
    const int cpb = (blockIdx.x >> 1) * 64;   // c' base (phi rows)
    const int cb  = (blockIdx.x & 1) * 64;    // c base (g rows)
    const int tid = threadIdx.x;
    const int tx = tid & 15, ty = tid >> 4;

    const float* phi = phi_g + ((size_t)b * CC) * SS;
    const float* g   = phi_g + ((size_t)b * CC + ICH) * SS;

    float acc[4][4] = {};
    for (int ks = 0; ks < 4; ++ks) {
        int s0 = kc * 256 + ks * 64;
        #pragma unroll
        for (int r = 0; r < 4; ++r) {             // 1024 float4 each operand
            int idx = tid + 256 * r;
            int row = idx >> 4, k4 = idx & 15;
            *(float4*)(&Ps[row][k4 * 4]) = *(const float4*)(phi + (size_t)(cpb + row) * SS + s0 + k4 * 4);
            *(float4*)(&Gs[row][k4 * 4]) = *(const float4*)(g   + (size_t)(cb  + row) * SS + s0 + k4 * 4);
        }
        __syncthreads();
        for (int k = 0; k < 64; k += 2) {
            float2 a[4], bb[4];
            #pragma unroll
            for (int i = 0; i < 4; ++i) a[i]  = *(const float2*)(&Ps[ty + 16 * i][k]);
            #pragma unroll
            for (int j = 0; j < 4; ++j) bb[j] = *(const float2*)(&Gs[tx + 16 * j][k]);
            #pragma unroll
            for (int i = 0; i < 4; ++i)
                #pragma unroll
                for (int j = 0; j < 4; ++j)
                    acc[i][j] += a[i].x * bb[j].x + a[i].y * bb[j].y;
        }
        __syncthreads();
    }
    float* dst = Mpart + (((size_t)b * 8 + kc) * ICH) * ICH;
    #pragma unroll
    for (int i = 0; i < 4; ++i)
        #pragma unroll
        for (int j = 0; j < 4; ++j)
            dst[(size_t)(cpb + ty + 16 * i) * ICH + cb + tx + 16 * j] = acc[i][j];
}

// ---------------------------------------------------------------------------
// k3a: Kb[b][co][c'] = (1/S) * sum_c w_w[co][c] * M[b][c'][c]   (M = sum of partials)
// grid (2 c'-tiles, 4 co-tiles, 8 b), block 256
// ---------------------------------------------------------------------------
__global__ __launch_bounds__(256) void k3a_kb(
    const float* __restrict__ w_w, const float* __restrict__ Mpart,
    float* __restrict__ Kb)
{
    __shared__ float Al[64][65];   // [k=c][co]
    __shared__ float Bl[64][65];   // [k=c][c']
    const int b = blockIdx.z;
    const int cob = blockIdx.y * 64;
    const int cpb = blockIdx.x * 64;
    const int tid = threadIdx.x;
    const int tx = tid & 15, ty = tid >> 4;

    float acc[4][4] = {};
    for (int kc2 = 0; kc2 < 2; ++kc2) {
        #pragma unroll
        for (int r = 0; r < 4; ++r) {
            int idx = tid + 256 * r;
            int row = idx >> 4, c4 = idx & 15;
            float4 v = *(const float4*)(w_w + (size_t)(cob + row) * ICH + kc2 * 64 + c4 * 4);
            Al[c4 * 4 + 0][row] = v.x; Al[c4 * 4 + 1][row] = v.y;
            Al[c4 * 4 + 2][row] = v.z; Al[c4 * 4 + 3][row] = v.w;
        }
        #pragma unroll
        for (int r = 0; r < 4; ++r) {
            int idx = tid + 256 * r;
            int row = idx >> 4, c4 = idx & 15;
            float4 s = {0.f, 0.f, 0.f, 0.f};
            #pragma unroll
            for (int kc = 0; kc < 8; ++kc) {
                float4 v = *(const float4*)(Mpart + (((size_t)b * 8 + kc) * ICH + cpb + row) * ICH + kc2 * 64 + c4 * 4);
                s.x += v.x; s.y += v.y; s.z += v.z; s.w += v.w;
            }
            Bl[c4 * 4 + 0][row] = s.x; Bl[c4 * 4 + 1][row] = s.y;
            Bl[c4 * 4 + 2][row] = s.z; Bl[c4 * 4 + 3][row] = s.w;
        }
        __syncthreads();
        for (int k = 0; k < 64; ++k) {
            float av[4], bv[4];
            #pragma unroll
            for (int i = 0; i < 4; ++i) av[i] = Al[k][ty + 16 * i];
            #pragma unroll
            for (int j = 0; j < 4; ++j) bv[j] = Bl[k][tx + 16 * j];
            #pragma unroll
            for (int i = 0; i < 4; ++i)
                #pragma unroll
                for (int j = 0; j < 4; ++j) acc[i][j] += av[i] * bv[j];
        }
        __syncthreads();
    }
    #pragma unroll
    for (int i = 0; i < 4; ++i)
        #pragma unroll
        for (int j = 0; j < 4; ++j)
            Kb[((size_t)b * CC + cob + ty + 16 * i) * ICH + cpb + tx + 16 * j] = acc[i][j] * INV_S;
}

// ---------------------------------------------------------------------------
// k3b: P[b][co][ci] = sum_{c'} Kb[b][co][c'] * theta_w[c'][ci]
// grid (2 ci-tiles(128), 4 co-tiles(64), 8 b), block 256
// ---------------------------------------------------------------------------
__global__ __launch_bounds__(256) void k3b_p(
    const float* __restrict__ Kb, const float* __restrict__ theta_w,
    float* __restrict__ P)
{
    __shared__ float Al[64][65];    // [k=c'][co]
    __shared__ float Bl[64][128];   // [k=c'][ci]
    const int b = blockIdx.z;
    const int cob = blockIdx.y * 64;
    const int cib = blockIdx.x * 128;
    const int tid = threadIdx.x;
    const int tx = tid & 15, ty = tid >> 4;

    float acc[4][8] = {};
    for (int kc2 = 0; kc2 < 2; ++kc2) {
        #pragma unroll
        for (int r = 0; r < 4; ++r) {
            int idx = tid + 256 * r;
            int row = idx >> 4, c4 = idx & 15;
            float4 v = *(const float4*)(Kb + ((size_t)b * CC + cob + row) * ICH + kc2 * 64 + c4 * 4);
            Al[c4 * 4 + 0][row] = v.x; Al[c4 * 4 + 1][row] = v.y;
            Al[c4 * 4 + 2][row] = v.z; Al[c4 * 4 + 3][row] = v.w;
        }
        #pragma unroll
        for (int r = 0; r < 8; ++r) {               // 64 rows x 32 float4
            int idx = tid + 256 * r;
            int row = idx >> 5, c4 = idx & 31;
            *(float4*)(&Bl[row][c4 * 4]) =
                *(const float4*)(theta_w + (size_t)(kc2 * 64 + row) * CC + cib + c4 * 4);
        }
        __syncthreads();
        for (int k = 0; k < 64; ++k) {
            float av[4], bv[8];
            #pragma unroll
            for (int i = 0; i < 4; ++i) av[i] = Al[k][ty + 16 * i];
            #pragma unroll
            for (int j = 0; j < 8; ++j) bv[j] = Bl[k][tx + 16 * j];
            #pragma unroll
            for (int i = 0; i < 4; ++i)
                #pragma unroll
                for (int j = 0; j < 8; ++j) acc[i][j] += av[i] * bv[j];
        }
        __syncthreads();
    }
    #pragma unroll
    for (int i = 0; i < 4; ++i)
        #pragma unroll
        for (int j = 0; j < 8; ++j)
            P[((size_t)b * CC + cob + ty + 16 * i) * CC + cib + tx + 16 * j] = acc[i][j];
}

// ---------------------------------------------------------------------------
// k3c: q[b][co] = w_b[co] + sum_{c'} Kb[b][co][c'] * theta_b[c']
// ---------------------------------------------------------------------------
__global__ __launch_bounds__(256) void k3c_q(
    const float* __restrict__ Kb, const float* __restrict__ theta_b,
    const float* __restrict__ w_b, float* __restrict__ q)
{
    __shared__ float tbs[ICH];
    const int b = blockIdx.x, co = threadIdx.x;
    if (co < ICH) tbs[co] = theta_b[co];
    __syncthreads();
    const float* kr = Kb + ((size_t)b * CC + co) * ICH;
    float s = w_b[co];
    for (int c = 0; c < ICH; ++c) s += kr[c] * tbs[c];
    q[b * CC + co] = s;
}

// ---------------------------------------------------------------------------
// k4: wy[b][c][t] = sum_ci P[b][c][ci] * x[b][ci][t] + q[b][c]; also BN partial stats
// grid (32 t-tiles, 4 c-tiles, 8 b), block 256
// ---------------------------------------------------------------------------
__global__ __launch_bounds__(256) void k4_wy(
    const float* __restrict__ x, const float* __restrict__ P,
    const float* __restrict__ q, float* __restrict__ wy,
    float* __restrict__ stats)      // [0..255]=sum, [256..511]=sumsq
{
    __shared__ float Xs[64][128];
    __shared__ float Al[64][65];    // [k=ci][co]
    const int b = blockIdx.z;
    const int cb = blockIdx.y * 64;
    const int tb = blockIdx.x * 128;
    const int tid = threadIdx.x;
    const int tx = tid & 15, ty = tid >> 4;

    float acc[4][8] = {};
    for (int kc = 0; kc < 4; ++kc) {
        const float* xsrc = x + ((size_t)b * CC + kc * 64) * TT + tb;
        #pragma unroll
        for (int r = 0; r < 8; ++r) {
            int idx = tid + 256 * r;
            int k = idx >> 5, c4 = idx & 31;
            *(float4*)(&Xs[k][c4 * 4]) = *(const float4*)(xsrc + (size_t)k * TT + c4 * 4);
        }
        #pragma unroll
        for (int r = 0; r < 4; ++r) {
            int idx = tid + 256 * r;
            int row = idx >> 4, c4 = idx & 15;
            float4 v = *(const float4*)(P + ((size_t)b * CC + cb + row) * CC + kc * 64 + c4 * 4);
            Al[c4 * 4 + 0][row] = v.x; Al[c4 * 4 + 1][row] = v.y;
            Al[c4 * 4 + 2][row] = v.z; Al[c4 * 4 + 3][row] = v.w;
        }
        __syncthreads();
        for (int k = 0; k < 64; ++k) {
            float av[4];
            #pragma unroll
            for (int i = 0; i < 4; ++i) av[i] = Al[k][ty + 16 * i];
            #pragma unroll
            for (int j = 0; j < 8; ++j) {
                float xv = Xs[k][tx + 16 * j];
                #pragma unroll
                for (int i = 0; i < 4; ++i) acc[i][j] += av[i] * xv;
            }
        }
        __syncthreads();
    }
    #pragma unroll
    for (int i = 0; i < 4; ++i) {
        int c = cb + ty + 16 * i;
        float bias = q[b * CC + c];
        float* dst = wy + ((size_t)b * CC + c) * TT + tb;
        float s1 = 0.f, s2 = 0.f;
        #pragma unroll
        for (int j = 0; j < 8; ++j) {
            float v = acc[i][j] + bias;
            dst[tx + 16 * j] = v;
            s1 += v; s2 += v * v;
        }
        #pragma unroll
        for (int off = 8; off > 0; off >>= 1) {
            s1 += __shfl_down(s1, off, 16);
            s2 += __shfl_down(s2, off, 16);
        }
        if (tx == 0) {
            atomicAdd(&stats[c], s1);
            atomicAdd(&stats[CC + c], s2);
        }
    }
}

// ---------------------------------------------------------------------------
// k5: per-channel BN coefficients  A = gamma*rsqrt(var+eps), B = beta - mean*A
// ---------------------------------------------------------------------------
__global__ void k5_bn(const float* __restrict__ stats, const float* __restrict__ gamma,
                      const float* __restrict__ beta, float* __restrict__ coef)
{
    int c = threadIdx.x;
    float mean = stats[c] * INV_BT;
    float var  = stats[CC + c] * INV_BT - mean * mean;
    float A = gamma[c] * rsqrtf(var + BN_EPS);
    coef[c] = A;
    coef[CC + c] = beta[c] - mean * A;
}

// ---------------------------------------------------------------------------
// k6: out = wy*A[c] + B[c] + x   (elementwise, float4)
// ---------------------------------------------------------------------------
__global__ __launch_bounds__(256) void k6_out(
    const float* __restrict__ wy, const float* __restrict__ x,
    const float* __restrict__ coef, float* __restrict__ out)
{
    size_t idx4 = (size_t)blockIdx.x * 256 + threadIdx.x;  // 2,097,152 total
    int c = (int)((idx4 >> 10) & 255);                     // T/4=1024 float4 per row
    float A = coef[c], Bc = coef[CC + c];
    float4 w = ((const float4*)wy)[idx4];
    float4 xv = ((const float4*)x)[idx4];
    float4 o;
    o.x = w.x * A + Bc + xv.x;
    o.y = w.y * A + Bc + xv.y;
    o.z = w.z * A + Bc + xv.z;
    o.w = w.w * A + Bc + xv.w;
    ((float4*)out)[idx4] = o;
}

extern "C" void kernel_launch(void* const* d_in, const int* in_sizes, int n_in,
                              void* d_out, int out_size, void* d_ws, size_t ws_size,
                              hipStream_t stream)
{
    const float* x        = (const float*)d_in[0];
    const float* theta_w  = (const float*)d_in[1];
    const float* theta_b  = (const float*)d_in[2];
    const float* phi_w    = (const float*)d_in[3];
    const float* phi_b    = (const float*)d_in[4];
    const float* g_w      = (const float*)d_in[5];
    const float* g_b      = (const float*)d_in[6];
    const float* w_w      = (const float*)d_in[7];
    const float* w_b      = (const float*)d_in[8];
    const float* bn_gamma = (const float*)d_in[9];
    const float* bn_beta  = (const float*)d_in[10];
    float* out = (float*)d_out;

    float* ws    = (float*)d_ws;
    float* phi_g = ws;                       // [8][256][2048]      = 4,194,304
    float* Mpart = phi_g + 4194304;          // [8][8][128][128]    = 1,048,576
    float* Kb    = Mpart + 1048576;          // [8][256][128]       =   262,144
    float* P     = Kb + 262144;              // [8][256][256]       =   524,288
    float* q     = P + 524288;               // [8][256]            =     2,048
    float* wy    = q + 2048;                 // [8][256][4096]      = 8,388,608
    float* stats = wy + 8388608;             // [2][256]            =       512
    float* coef  = stats + 512;              // [2][256]            =       512

    hipMemsetAsync(stats, 0, 512 * sizeof(float), stream);

    k1_conv_pool<<<dim3(32, 4, 8), 256, 0, stream>>>(x, phi_w, phi_b, g_w, g_b, phi_g);
    k2_gram<<<dim3(4, 8, 8), 256, 0, stream>>>(phi_g, Mpart);
    k3a_kb<<<dim3(2, 4, 8), 256, 0, stream>>>(w_w, Mpart, Kb);
    k3b_p<<<dim3(2, 4, 8), 256, 0, stream>>>(Kb, theta_w, P);
    k3c_q<<<dim3(8), 256, 0, stream>>>(Kb, theta_b, w_b, q);
    k4_wy<<<dim3(32, 4, 8), 256, 0, stream>>>(x, P, q, wy, stats);
    k5_bn<<<dim3(1), 256, 0, stream>>>(stats, bn_gamma, bn_beta, coef);
    k6_out<<<dim3(8192), 256, 0, stream>>>(wy, x, coef, out);
}

// Round 2
// 256.721 us; speedup vs baseline: 1.1682x; 1.1682x over previous
//
#include <hip/hip_runtime.h>
#include <hip/hip_bf16.h>

typedef __attribute__((ext_vector_type(8))) short short8;
typedef __attribute__((ext_vector_type(4))) short short4v;
typedef __attribute__((ext_vector_type(4))) float floatx4;

#define BB 8
#define CC 256
#define ICH 128
#define TT 4096
#define SS 2048
static constexpr float BN_EPS = 1e-5f;
static constexpr float INV_S  = 1.0f / 2048.0f;
static constexpr float INV_BT = 1.0f / 32768.0f;   // 1/(B*T)

// ---------------------------------------------------------------------------
// k0x: transpose + convert  x[b][c][t] (f32)  ->  xt[b][t][c] (bf16)
// grid (64 t-tiles, 4 c-tiles, 8 b), block 256, tile 64x64
// ---------------------------------------------------------------------------
__global__ __launch_bounds__(256) void k0x_transpose(
    const float* __restrict__ x, __hip_bfloat16* __restrict__ xt)
{
    __shared__ float Tl[64][65];
    const int b = blockIdx.z, cb = blockIdx.y * 64, tb = blockIdx.x * 64;
    const int tid = threadIdx.x;
    #pragma unroll
    for (int it = 0; it < 4; ++it) {
        int idx = tid + 256 * it;
        int row = idx >> 4, c4 = idx & 15;
        float4 v = *(const float4*)(x + ((size_t)b * CC + cb + row) * TT + tb + c4 * 4);
        Tl[row][c4 * 4 + 0] = v.x; Tl[row][c4 * 4 + 1] = v.y;
        Tl[row][c4 * 4 + 2] = v.z; Tl[row][c4 * 4 + 3] = v.w;
    }
    __syncthreads();
    #pragma unroll
    for (int it = 0; it < 2; ++it) {
        int idx = tid + 256 * it;
        int trow = idx >> 3, ch = idx & 7;
        alignas(16) __hip_bfloat16 tmp[8];
        #pragma unroll
        for (int e = 0; e < 8; ++e) tmp[e] = __float2bfloat16(Tl[ch * 8 + e][trow]);
        *(short8*)(xt + ((size_t)b * TT + tb + trow) * CC + cb + ch * 8) = *(const short8*)tmp;
    }
}

// ---------------------------------------------------------------------------
// k0w: convert phi_w,g_w -> stacked bf16 Wf[256][256]
// ---------------------------------------------------------------------------
__global__ __launch_bounds__(256) void k0w_conv(
    const float* __restrict__ phi_w, const float* __restrict__ g_w,
    __hip_bfloat16* __restrict__ Wf)
{
    int idx = blockIdx.x * 256 + threadIdx.x;       // 0..16383, 4 floats each
    const float* src = (idx < 8192) ? (phi_w + (size_t)idx * 4)
                                    : (g_w + (size_t)(idx - 8192) * 4);
    float4 v = *(const float4*)src;
    alignas(8) __hip_bfloat16 t[4];
    t[0] = __float2bfloat16(v.x); t[1] = __float2bfloat16(v.y);
    t[2] = __float2bfloat16(v.z); t[3] = __float2bfloat16(v.w);
    *(short4v*)(Wf + (size_t)idx * 4) = *(const short4v*)t;
}

// ---------------------------------------------------------------------------
// k1: MFMA conv1x1 (stacked phi|g) + maxpool2 epilogue.
// out[o][t] = sum_c Wf[o][c] * xt[t][c]; pool pairs via even/odd column tiles.
// grid (32 t-tiles of 128, 2 m-tiles of 128, 8 b), block 256 (4 waves)
// ---------------------------------------------------------------------------
__global__ __launch_bounds__(256) void k1_mfma(
    const __hip_bfloat16* __restrict__ Wf, const float* __restrict__ phi_b,
    const float* __restrict__ g_b, const __hip_bfloat16* __restrict__ xt,
    __hip_bfloat16* __restrict__ phi_g)
{
    __shared__ short lds[2 * 128 * 64];       // As | Bs, 32 KB
    short* As = lds;
    short* Bs = lds + 128 * 64;

    const int b  = blockIdx.z;
    const int m0 = blockIdx.y * 128;
    const int t0 = blockIdx.x * 128;
    const int tid = threadIdx.x;
    const int w = tid >> 6, l = tid & 63;
    const int quad = l >> 4, lm = l & 15;
    const int wm = (w & 1) * 64, wn = (w >> 1) * 64;

    floatx4 acc[4][4];
    #pragma unroll
    for (int i = 0; i < 4; ++i)
        #pragma unroll
        for (int j = 0; j < 4; ++j) acc[i][j] = (floatx4)0.f;

    const __hip_bfloat16* Abase = Wf + (size_t)m0 * CC;
    const __hip_bfloat16* Bbase = xt + (size_t)b * TT * CC;

    for (int k0 = 0; k0 < CC; k0 += 64) {
        #pragma unroll
        for (int it = 0; it < 4; ++it) {
            int idx = tid + 256 * it;
            int row = idx >> 3, ch = idx & 7;
            *(short8*)&As[row * 64 + ch * 8] =
                *(const short8*)(Abase + (size_t)row * CC + k0 + ch * 8);
            // B staged with pooling permutation: col tile 2u -> even t, 2u+1 -> odd t
            int h = row >> 6, rem = row & 63, jt = rem >> 4, n = rem & 15;
            int t_off = h * 64 + (jt >> 1) * 32 + (jt & 1) + 2 * n;
            *(short8*)&Bs[row * 64 + ch * 8] =
                *(const short8*)(Bbase + (size_t)(t0 + t_off) * CC + k0 + ch * 8);
        }
        __syncthreads();
        #pragma unroll
        for (int ks = 0; ks < 2; ++ks) {
            short8 a[4], bb[4];
            #pragma unroll
            for (int i = 0; i < 4; ++i)
                a[i] = *(const short8*)&As[(wm + i * 16 + lm) * 64 + ks * 32 + quad * 8];
            #pragma unroll
            for (int j = 0; j < 4; ++j)
                bb[j] = *(const short8*)&Bs[(wn + j * 16 + lm) * 64 + ks * 32 + quad * 8];
            #pragma unroll
            for (int i = 0; i < 4; ++i)
                #pragma unroll
                for (int j = 0; j < 4; ++j)
                    acc[i][j] = __builtin_amdgcn_mfma_f32_16x16x32_bf16(a[i], bb[j], acc[i][j], 0, 0, 0);
        }
        __syncthreads();
    }

    // epilogue: lane-local pool of even/odd tiles, +bias, LDS-stage, coalesced store
    __hip_bfloat16* Out = (__hip_bfloat16*)lds;   // 128 x 64 bf16 (16 KB)
    #pragma unroll
    for (int i = 0; i < 4; ++i) {
        #pragma unroll
        for (int u = 0; u < 2; ++u) {
            #pragma unroll
            for (int r = 0; r < 4; ++r) {
                int m = wm + i * 16 + quad * 4 + r;
                int o = m0 + m;
                float bias = (o < ICH) ? phi_b[o] : g_b[o - ICH];
                float p = fmaxf(acc[i][2 * u][r], acc[i][2 * u + 1][r]) + bias;
                Out[m * 64 + (wn >> 1) + u * 16 + lm] = __float2bfloat16(p);
            }
        }
    }
    __syncthreads();
    const int s0 = blockIdx.x * 64;
    #pragma unroll
    for (int it = 0; it < 4; ++it) {
        int idx = tid + 256 * it;
        int row = idx >> 3, ch = idx & 7;
        *(short8*)(phi_g + ((size_t)b * CC + m0 + row) * SS + s0 + ch * 8) =
            *(const short8*)&Out[row * 64 + ch * 8];
    }
}

// ---------------------------------------------------------------------------
// k2: MFMA Gram partials  Mpart[b][kc][c'][c] = sum_{s in 256-chunk} phi[c'][s] g[c][s]
// grid (8 kc, 8 b), block 256
// ---------------------------------------------------------------------------
__global__ __launch_bounds__(256) void k2_mfma(
    const __hip_bfloat16* __restrict__ phi_g, float* __restrict__ Mpart)
{
    __shared__ short lds[2 * 128 * 64];
    short* As = lds;
    short* Bs = lds + 128 * 64;
    const int kc = blockIdx.x, b = blockIdx.y;
    const int tid = threadIdx.x;
    const int w = tid >> 6, l = tid & 63;
    const int quad = l >> 4, lm = l & 15;
    const int wm = (w & 1) * 64, wn = (w >> 1) * 64;

    const __hip_bfloat16* Abase = phi_g + ((size_t)b * CC) * SS + kc * 256;        // phi rows
    const __hip_bfloat16* Bbase = phi_g + ((size_t)b * CC + ICH) * SS + kc * 256;  // g rows

    floatx4 acc[4][4];
    #pragma unroll
    for (int i = 0; i < 4; ++i)
        #pragma unroll
        for (int j = 0; j < 4; ++j) acc[i][j] = (floatx4)0.f;

    for (int k0 = 0; k0 < 256; k0 += 64) {
        #pragma unroll
        for (int it = 0; it < 4; ++it) {
            int idx = tid + 256 * it;
            int row = idx >> 3, ch = idx & 7;
            *(short8*)&As[row * 64 + ch * 8] =
                *(const short8*)(Abase + (size_t)row * SS + k0 + ch * 8);
            *(short8*)&Bs[row * 64 + ch * 8] =
                *(const short8*)(Bbase + (size_t)row * SS + k0 + ch * 8);
        }
        __syncthreads();
        #pragma unroll
        for (int ks = 0; ks < 2; ++ks) {
            short8 a[4], bb[4];
            #pragma unroll
            for (int i = 0; i < 4; ++i)
                a[i] = *(const short8*)&As[(wm + i * 16 + lm) * 64 + ks * 32 + quad * 8];
            #pragma unroll
            for (int j = 0; j < 4; ++j)
                bb[j] = *(const short8*)&Bs[(wn + j * 16 + lm) * 64 + ks * 32 + quad * 8];
            #pragma unroll
            for (int i = 0; i < 4; ++i)
                #pragma unroll
                for (int j = 0; j < 4; ++j)
                    acc[i][j] = __builtin_amdgcn_mfma_f32_16x16x32_bf16(a[i], bb[j], acc[i][j], 0, 0, 0);
        }
        __syncthreads();
    }

    float* dst = Mpart + (((size_t)b * 8 + kc) * ICH) * ICH;
    #pragma unroll
    for (int i = 0; i < 4; ++i)
        #pragma unroll
        for (int j = 0; j < 4; ++j)
            #pragma unroll
            for (int r = 0; r < 4; ++r) {
                int m = wm + i * 16 + quad * 4 + r;
                int n = wn + j * 16 + lm;
                dst[(size_t)m * ICH + n] = acc[i][j][r];
            }
}

// ---------------------------------------------------------------------------
// k3a: Kb[b][co][c'] = (1/S) * sum_c w_w[co][c] * M[b][c'][c]   (fp32 VALU, small)
// ---------------------------------------------------------------------------
__global__ __launch_bounds__(256) void k3a_kb(
    const float* __restrict__ w_w, const float* __restrict__ Mpart,
    float* __restrict__ Kb)
{
    __shared__ float Al[64][65];
    __shared__ float Bl[64][65];
    const int b = blockIdx.z;
    const int cob = blockIdx.y * 64;
    const int cpb = blockIdx.x * 64;
    const int tid = threadIdx.x;
    const int tx = tid & 15, ty = tid >> 4;

    float acc[4][4] = {};
    for (int kc2 = 0; kc2 < 2; ++kc2) {
        #pragma unroll
        for (int r = 0; r < 4; ++r) {
            int idx = tid + 256 * r;
            int row = idx >> 4, c4 = idx & 15;
            float4 v = *(const float4*)(w_w + (size_t)(cob + row) * ICH + kc2 * 64 + c4 * 4);
            Al[c4 * 4 + 0][row] = v.x; Al[c4 * 4 + 1][row] = v.y;
            Al[c4 * 4 + 2][row] = v.z; Al[c4 * 4 + 3][row] = v.w;
        }
        #pragma unroll
        for (int r = 0; r < 4; ++r) {
            int idx = tid + 256 * r;
            int row = idx >> 4, c4 = idx & 15;
            float4 s = {0.f, 0.f, 0.f, 0.f};
            #pragma unroll
            for (int kc = 0; kc < 8; ++kc) {
                float4 v = *(const float4*)(Mpart + (((size_t)b * 8 + kc) * ICH + cpb + row) * ICH + kc2 * 64 + c4 * 4);
                s.x += v.x; s.y += v.y; s.z += v.z; s.w += v.w;
            }
            Bl[c4 * 4 + 0][row] = s.x; Bl[c4 * 4 + 1][row] = s.y;
            Bl[c4 * 4 + 2][row] = s.z; Bl[c4 * 4 + 3][row] = s.w;
        }
        __syncthreads();
        for (int k = 0; k < 64; ++k) {
            float av[4], bv[4];
            #pragma unroll
            for (int i = 0; i < 4; ++i) av[i] = Al[k][ty + 16 * i];
            #pragma unroll
            for (int j = 0; j < 4; ++j) bv[j] = Bl[k][tx + 16 * j];
            #pragma unroll
            for (int i = 0; i < 4; ++i)
                #pragma unroll
                for (int j = 0; j < 4; ++j) acc[i][j] += av[i] * bv[j];
        }
        __syncthreads();
    }
    #pragma unroll
    for (int i = 0; i < 4; ++i)
        #pragma unroll
        for (int j = 0; j < 4; ++j)
            Kb[((size_t)b * CC + cob + ty + 16 * i) * ICH + cpb + tx + 16 * j] = acc[i][j] * INV_S;
}

// ---------------------------------------------------------------------------
// k3b: P[b][co][ci] = sum_{c'} Kb[b][co][c'] * theta_w[c'][ci]   (bf16 output)
// ---------------------------------------------------------------------------
__global__ __launch_bounds__(256) void k3b_p(
    const float* __restrict__ Kb, const float* __restrict__ theta_w,
    __hip_bfloat16* __restrict__ P)
{
    __shared__ float Al[64][65];
    __shared__ float Bl[64][128];
    const int b = blockIdx.z;
    const int cob = blockIdx.y * 64;
    const int cib = blockIdx.x * 128;
    const int tid = threadIdx.x;
    const int tx = tid & 15, ty = tid >> 4;

    float acc[4][8] = {};
    for (int kc2 = 0; kc2 < 2; ++kc2) {
        #pragma unroll
        for (int r = 0; r < 4; ++r) {
            int idx = tid + 256 * r;
            int row = idx >> 4, c4 = idx & 15;
            float4 v = *(const float4*)(Kb + ((size_t)b * CC + cob + row) * ICH + kc2 * 64 + c4 * 4);
            Al[c4 * 4 + 0][row] = v.x; Al[c4 * 4 + 1][row] = v.y;
            Al[c4 * 4 + 2][row] = v.z; Al[c4 * 4 + 3][row] = v.w;
        }
        #pragma unroll
        for (int r = 0; r < 8; ++r) {
            int idx = tid + 256 * r;
            int row = idx >> 5, c4 = idx & 31;
            *(float4*)(&Bl[row][c4 * 4]) =
                *(const float4*)(theta_w + (size_t)(kc2 * 64 + row) * CC + cib + c4 * 4);
        }
        __syncthreads();
        for (int k = 0; k < 64; ++k) {
            float av[4], bv[8];
            #pragma unroll
            for (int i = 0; i < 4; ++i) av[i] = Al[k][ty + 16 * i];
            #pragma unroll
            for (int j = 0; j < 8; ++j) bv[j] = Bl[k][tx + 16 * j];
            #pragma unroll
            for (int i = 0; i < 4; ++i)
                #pragma unroll
                for (int j = 0; j < 8; ++j) acc[i][j] += av[i] * bv[j];
        }
        __syncthreads();
    }
    #pragma unroll
    for (int i = 0; i < 4; ++i)
        #pragma unroll
        for (int j = 0; j < 8; ++j)
            P[((size_t)b * CC + cob + ty + 16 * i) * CC + cib + tx + 16 * j] =
                __float2bfloat16(acc[i][j]);
}

// ---------------------------------------------------------------------------
// k3c: q[b][co] = w_b[co] + sum_{c'} Kb[b][co][c'] * theta_b[c']
// ---------------------------------------------------------------------------
__global__ __launch_bounds__(256) void k3c_q(
    const float* __restrict__ Kb, const float* __restrict__ theta_b,
    const float* __restrict__ w_b, float* __restrict__ q)
{
    __shared__ float tbs[ICH];
    const int b = blockIdx.x, co = threadIdx.x;
    if (co < ICH) tbs[co] = theta_b[co];
    __syncthreads();
    const float* kr = Kb + ((size_t)b * CC + co) * ICH;
    float s = w_b[co];
    for (int c = 0; c < ICH; ++c) s += kr[c] * tbs[c];
    q[b * CC + co] = s;
}

// ---------------------------------------------------------------------------
// k4: MFMA  wy[b][c][t] = sum_ci P[b][c][ci] * xt[b][t][ci] + q[b][c]
//     + BN partial stats; wy stored bf16 via LDS-staged coalesced writes
// grid (32 t-tiles, 2 m-tiles, 8 b), block 256
// ---------------------------------------------------------------------------
__global__ __launch_bounds__(256) void k4_mfma(
    const __hip_bfloat16* __restrict__ P, const __hip_bfloat16* __restrict__ xt,
    const float* __restrict__ q, __hip_bfloat16* __restrict__ wy,
    float* __restrict__ stats)
{
    __shared__ short lds[2 * 128 * 64];
    short* As = lds;
    short* Bs = lds + 128 * 64;

    const int b  = blockIdx.z;
    const int m0 = blockIdx.y * 128;
    const int t0 = blockIdx.x * 128;
    const int tid = threadIdx.x;
    const int w = tid >> 6, l = tid & 63;
    const int quad = l >> 4, lm = l & 15;
    const int wm = (w & 1) * 64, wn = (w >> 1) * 64;

    floatx4 acc[4][4];
    #pragma unroll
    for (int i = 0; i < 4; ++i)
        #pragma unroll
        for (int j = 0; j < 4; ++j) acc[i][j] = (floatx4)0.f;

    const __hip_bfloat16* Abase = P + ((size_t)b * CC + m0) * CC;
    const __hip_bfloat16* Bbase = xt + ((size_t)b * TT + t0) * CC;

    for (int k0 = 0; k0 < CC; k0 += 64) {
        #pragma unroll
        for (int it = 0; it < 4; ++it) {
            int idx = tid + 256 * it;
            int row = idx >> 3, ch = idx & 7;
            *(short8*)&As[row * 64 + ch * 8] =
                *(const short8*)(Abase + (size_t)row * CC + k0 + ch * 8);
            *(short8*)&Bs[row * 64 + ch * 8] =
                *(const short8*)(Bbase + (size_t)row * CC + k0 + ch * 8);
        }
        __syncthreads();
        #pragma unroll
        for (int ks = 0; ks < 2; ++ks) {
            short8 a[4], bb[4];
            #pragma unroll
            for (int i = 0; i < 4; ++i)
                a[i] = *(const short8*)&As[(wm + i * 16 + lm) * 64 + ks * 32 + quad * 8];
            #pragma unroll
            for (int j = 0; j < 4; ++j)
                bb[j] = *(const short8*)&Bs[(wn + j * 16 + lm) * 64 + ks * 32 + quad * 8];
            #pragma unroll
            for (int i = 0; i < 4; ++i)
                #pragma unroll
                for (int j = 0; j < 4; ++j)
                    acc[i][j] = __builtin_amdgcn_mfma_f32_16x16x32_bf16(a[i], bb[j], acc[i][j], 0, 0, 0);
        }
        __syncthreads();
    }

    // epilogue: +q bias, partial BN stats, LDS-stage bf16 tile, coalesced store
    __hip_bfloat16* Out = (__hip_bfloat16*)lds;   // 128 x 128 bf16 (32 KB)
    #pragma unroll
    for (int i = 0; i < 4; ++i) {
        float s1[4] = {0.f, 0.f, 0.f, 0.f}, s2[4] = {0.f, 0.f, 0.f, 0.f};
        #pragma unroll
        for (int j = 0; j < 4; ++j) {
            #pragma unroll
            for (int r = 0; r < 4; ++r) {
                int m = wm + i * 16 + quad * 4 + r;
                float v = acc[i][j][r] + q[b * CC + m0 + m];
                s1[r] += v; s2[r] += v * v;
                Out[m * 128 + wn + j * 16 + lm] = __float2bfloat16(v);
            }
        }
        #pragma unroll
        for (int r = 0; r < 4; ++r) {
            float a1 = s1[r], a2 = s2[r];
            #pragma unroll
            for (int off = 1; off < 16; off <<= 1) {
                a1 += __shfl_xor(a1, off);
                a2 += __shfl_xor(a2, off);
            }
            if (lm == 0) {
                int c = m0 + wm + i * 16 + quad * 4 + r;
                atomicAdd(&stats[c], a1);
                atomicAdd(&stats[CC + c], a2);
            }
        }
    }
    __syncthreads();
    #pragma unroll
    for (int it = 0; it < 8; ++it) {
        int idx = tid + 256 * it;
        int row = idx >> 4, ch = idx & 15;
        *(short8*)(wy + ((size_t)b * CC + m0 + row) * TT + t0 + ch * 8) =
            *(const short8*)&Out[row * 128 + ch * 8];
    }
}

// ---------------------------------------------------------------------------
// k5: BN coefficients
// ---------------------------------------------------------------------------
__global__ void k5_bn(const float* __restrict__ stats, const float* __restrict__ gamma,
                      const float* __restrict__ beta, float* __restrict__ coef)
{
    int c = threadIdx.x;
    float mean = stats[c] * INV_BT;
    float var  = stats[CC + c] * INV_BT - mean * mean;
    float A = gamma[c] * rsqrtf(var + BN_EPS);
    coef[c] = A;
    coef[CC + c] = beta[c] - mean * A;
}

// ---------------------------------------------------------------------------
// k6: out = wy_bf16 * A[c] + B[c] + x   (8 elems/thread)
// ---------------------------------------------------------------------------
__global__ __launch_bounds__(256) void k6_out(
    const __hip_bfloat16* __restrict__ wy, const float* __restrict__ x,
    const float* __restrict__ coef, float* __restrict__ out)
{
    size_t idx = (size_t)blockIdx.x * 256 + threadIdx.x;   // 1,048,576 threads
    int c = (int)((idx >> 9) & 255);                       // 512 chunks of 8 per row
    float A = coef[c], Bc = coef[CC + c];
    short8 wv = *(const short8*)(wy + idx * 8);
    const __hip_bfloat16* wb = (const __hip_bfloat16*)&wv;
    const float4* xp = (const float4*)(x + idx * 8);
    float4 x0 = xp[0], x1 = xp[1];
    float4 o0, o1;
    o0.x = __bfloat162float(wb[0]) * A + Bc + x0.x;
    o0.y = __bfloat162float(wb[1]) * A + Bc + x0.y;
    o0.z = __bfloat162float(wb[2]) * A + Bc + x0.z;
    o0.w = __bfloat162float(wb[3]) * A + Bc + x0.w;
    o1.x = __bfloat162float(wb[4]) * A + Bc + x1.x;
    o1.y = __bfloat162float(wb[5]) * A + Bc + x1.y;
    o1.z = __bfloat162float(wb[6]) * A + Bc + x1.z;
    o1.w = __bfloat162float(wb[7]) * A + Bc + x1.w;
    float4* op = (float4*)(out + idx * 8);
    op[0] = o0; op[1] = o1;
}

extern "C" void kernel_launch(void* const* d_in, const int* in_sizes, int n_in,
                              void* d_out, int out_size, void* d_ws, size_t ws_size,
                              hipStream_t stream)
{
    const float* x        = (const float*)d_in[0];
    const float* theta_w  = (const float*)d_in[1];
    const float* theta_b  = (const float*)d_in[2];
    const float* phi_w    = (const float*)d_in[3];
    const float* phi_b    = (const float*)d_in[4];
    const float* g_w      = (const float*)d_in[5];
    const float* g_b      = (const float*)d_in[6];
    const float* w_w      = (const float*)d_in[7];
    const float* w_b      = (const float*)d_in[8];
    const float* bn_gamma = (const float*)d_in[9];
    const float* bn_beta  = (const float*)d_in[10];
    float* out = (float*)d_out;

    char* p = (char*)d_ws;
    __hip_bfloat16* xt    = (__hip_bfloat16*)p; p += (size_t)8388608 * 2;  // [8][4096][256]
    __hip_bfloat16* Wf    = (__hip_bfloat16*)p; p += (size_t)65536 * 2;    // [256][256]
    __hip_bfloat16* phi_g = (__hip_bfloat16*)p; p += (size_t)4194304 * 2;  // [8][256][2048]
    __hip_bfloat16* P     = (__hip_bfloat16*)p; p += (size_t)524288 * 2;   // [8][256][256]
    float* Mpart = (float*)p; p += (size_t)1048576 * 4;                    // [8][8][128][128]
    float* Kb    = (float*)p; p += (size_t)262144 * 4;                     // [8][256][128]
    float* q     = (float*)p; p += (size_t)2048 * 4;                       // [8][256]
    __hip_bfloat16* wy = (__hip_bfloat16*)p; p += (size_t)8388608 * 2;     // [8][256][4096]
    float* stats = (float*)p; p += (size_t)512 * 4;
    float* coef  = (float*)p;

    hipMemsetAsync(stats, 0, 512 * sizeof(float), stream);

    k0x_transpose<<<dim3(64, 4, 8), 256, 0, stream>>>(x, xt);
    k0w_conv<<<dim3(64), 256, 0, stream>>>(phi_w, g_w, Wf);
    k1_mfma<<<dim3(32, 2, 8), 256, 0, stream>>>(Wf, phi_b, g_b, xt, phi_g);
    k2_mfma<<<dim3(8, 8), 256, 0, stream>>>(phi_g, Mpart);
    k3a_kb<<<dim3(2, 4, 8), 256, 0, stream>>>(w_w, Mpart, Kb);
    k3b_p<<<dim3(2, 4, 8), 256, 0, stream>>>(Kb, theta_w, P);
    k3c_q<<<dim3(8), 256, 0, stream>>>(Kb, theta_b, w_b, q);
    k4_mfma<<<dim3(32, 2, 8), 256, 0, stream>>>(P, xt, q, wy, stats);
    k5_bn<<<dim3(1), 256, 0, stream>>>(stats, bn_gamma, bn_beta, coef);
    k6_out<<<dim3(4096), 256, 0, stream>>>(wy, x, coef, out);
}